// Round 3
// baseline (550.002 us; speedup 1.0000x reference)
//
#include <hip/hip_runtime.h>
#include <math.h>

// Problem constants: x (8, 64, 256, 256) fp32
#define NB 8
#define NC 64
#define NH 256
#define NW 256

// ---------------------------------------------------------------------------
// Generic 4x4 max-pool (stride 4). Input: channels [cOff, cOff+C) of an
// inC-channel HxH tensor. Output: (B, C, H/4, H/4) contiguous.
// ---------------------------------------------------------------------------
__global__ void pool4_kernel(const float* __restrict__ in, float* __restrict__ out,
                             int inC, int cOff, int C, int H, int total) {
    int idx = blockIdx.x * blockDim.x + threadIdx.x;
    if (idx >= total) return;
    int Ho = H >> 2;
    int pw = idx % Ho;
    int t  = idx / Ho;
    int ph = t % Ho;  t /= Ho;
    int c  = t % C;
    int b  = t / C;
    const float* src = in + (((size_t)b * inC + cOff + c) * H + ph * 4) * H + pw * 4;
    float m = -INFINITY;
#pragma unroll
    for (int i = 0; i < 4; ++i) {
        float4 v = *reinterpret_cast<const float4*>(src + (size_t)i * H);
        m = fmaxf(m, fmaxf(fmaxf(v.x, v.y), fmaxf(v.z, v.w)));
    }
    out[idx] = m;
}

// ---------------------------------------------------------------------------
// Generic depthwise 3x3, pad=1. Input: first C channels of an inC-channel
// HxH tensor. Output: (B, C, H, H) contiguous.
// ---------------------------------------------------------------------------
__global__ void dwconv_kernel(const float* __restrict__ in, const float* __restrict__ wgt,
                              const float* __restrict__ bias, float* __restrict__ out,
                              int inC, int C, int H, int total) {
    int idx = blockIdx.x * blockDim.x + threadIdx.x;
    if (idx >= total) return;
    int xw = idx % H;
    int t  = idx / H;
    int yh = t % H;  t /= H;
    int c  = t % C;
    int b  = t / C;
    const float* src = in + ((size_t)b * inC + c) * (size_t)(H * H);
    float acc = bias[c];
#pragma unroll
    for (int dy = -1; dy <= 1; ++dy) {
        int yy = yh + dy;
        if (yy < 0 || yy >= H) continue;
#pragma unroll
        for (int dx = -1; dx <= 1; ++dx) {
            int xx = xw + dx;
            if (xx < 0 || xx >= H) continue;
            acc += src[(size_t)yy * H + xx] * wgt[c * 9 + (dy + 1) * 3 + (dx + 1)];
        }
    }
    out[idx] = acc;
}

// ---------------------------------------------------------------------------
// Fused main kernel: per pixel (b,h,w)
//   cat[0:32]  = dwconv3x3(x[:, :32]) at full res (computed here)
//   cat[32:48] = up4(x2c), cat[48:56] = up16(x3c), cat[56:64] = up64(x4c)
//   agg[o] = ba[o] + sum_c wa[o,c] * cat[c]
//   out[o] = gelu_exact(agg[o]) * x[b,o,h,w]
// One thread per pixel; block of 256 = one image row (coalesced).
// ---------------------------------------------------------------------------
__launch_bounds__(256)
__global__ void fused_main(const float* __restrict__ x,
                           const float* __restrict__ w1, const float* __restrict__ b1,
                           const float* __restrict__ x2c,
                           const float* __restrict__ x3c,
                           const float* __restrict__ x4c,
                           const float* __restrict__ wa, const float* __restrict__ ba,
                           float* __restrict__ out) {
    int idx = blockIdx.x * 256 + threadIdx.x;   // 8*256*256 = 524288 pixels
    int w = idx & 255;
    int h = (idx >> 8) & 255;
    int b = idx >> 16;

    const size_t plane = (size_t)NH * NW;
    const float* xb_base = x + (size_t)b * NC * plane;

    float cat[64];

    // --- x1: depthwise 3x3 over channels 0..31, pad=1 ---
    bool hv0 = (h > 0), hv2 = (h < NH - 1);
    bool wv0 = (w > 0), wv2 = (w < NW - 1);
    int r0 = (h - 1) * NW, r1 = h * NW, r2 = (h + 1) * NW;
#pragma unroll
    for (int c = 0; c < 32; ++c) {
        const float* src = xb_base + (size_t)c * plane;
        const float* wc = w1 + c * 9;
        float acc = b1[c];
        if (hv0) {
            if (wv0) acc += src[r0 + w - 1] * wc[0];
            acc += src[r0 + w] * wc[1];
            if (wv2) acc += src[r0 + w + 1] * wc[2];
        }
        {
            if (wv0) acc += src[r1 + w - 1] * wc[3];
            acc += src[r1 + w] * wc[4];
            if (wv2) acc += src[r1 + w + 1] * wc[5];
        }
        if (hv2) {
            if (wv0) acc += src[r2 + w - 1] * wc[6];
            acc += src[r2 + w] * wc[7];
            if (wv2) acc += src[r2 + w + 1] * wc[8];
        }
        cat[c] = acc;
    }

    // --- upsampled pyramid levels (nearest) ---
    int h4 = h >> 2, w4 = w >> 2;
#pragma unroll
    for (int c = 0; c < 16; ++c)
        cat[32 + c] = x2c[(((size_t)b * 16 + c) * 64 + h4) * 64 + w4];
    int h16 = h >> 4, w16 = w >> 4;
#pragma unroll
    for (int c = 0; c < 8; ++c)
        cat[48 + c] = x3c[(((size_t)b * 8 + c) * 16 + h16) * 16 + w16];
    int h64 = h >> 6, w64 = w >> 6;
#pragma unroll
    for (int c = 0; c < 8; ++c)
        cat[56 + c] = x4c[(((size_t)b * 8 + c) * 4 + h64) * 4 + w64];

    // --- channel mix + exact GELU + gating multiply ---
    const size_t pix = (size_t)h * NW + w;
    for (int o = 0; o < 64; ++o) {
        float acc = ba[o];
        const float* wr = wa + o * 64;   // wave-uniform address -> scalar loads
#pragma unroll
        for (int c = 0; c < 64; ++c)
            acc += wr[c] * cat[c];
        float g = 0.5f * acc * (1.0f + erff(acc * 0.70710678118654752f));
        size_t off = ((size_t)b * NC + o) * plane + pix;
        out[off] = g * x[off];
    }
}

extern "C" void kernel_launch(void* const* d_in, const int* in_sizes, int n_in,
                              void* d_out, int out_size, void* d_ws, size_t ws_size,
                              hipStream_t stream) {
    const float* x  = (const float*)d_in[0];
    const float* w1 = (const float*)d_in[1];
    const float* b1 = (const float*)d_in[2];
    const float* w2 = (const float*)d_in[3];
    const float* b2 = (const float*)d_in[4];
    const float* w3 = (const float*)d_in[5];
    const float* b3 = (const float*)d_in[6];
    const float* w4 = (const float*)d_in[7];
    const float* b4 = (const float*)d_in[8];
    const float* wa = (const float*)d_in[9];
    const float* ba = (const float*)d_in[10];
    float* out = (float*)d_out;

    // Workspace layout (floats)
    float* ws   = (float*)d_ws;
    float* p2   = ws;                       // 8*32*64*64 = 1048576
    float* x2c  = p2  + 1048576;            // 8*16*64*64 = 524288
    float* p3   = x2c + 524288;             // 8*16*16*16 = 32768
    float* x3c  = p3  + 32768;              // 8*8*16*16  = 16384
    float* p4   = x3c + 16384;              // 8*8*4*4    = 1024
    float* x4c  = p4  + 1024;               // 8*8*4*4    = 1024

    // p2 = maxpool4(x[:, 32:64])  -> (8,32,64,64)
    {
        int total = NB * 32 * 64 * 64;
        pool4_kernel<<<(total + 255) / 256, 256, 0, stream>>>(x, p2, 64, 32, 32, 256, total);
    }
    // x2c = dwconv3x3(p2[:, :16], w2, b2) -> (8,16,64,64)
    {
        int total = NB * 16 * 64 * 64;
        dwconv_kernel<<<(total + 255) / 256, 256, 0, stream>>>(p2, w2, b2, x2c, 32, 16, 64, total);
    }
    // p3 = maxpool4(p2[:, 16:32]) -> (8,16,16,16)
    {
        int total = NB * 16 * 16 * 16;
        pool4_kernel<<<(total + 255) / 256, 256, 0, stream>>>(p2, p3, 32, 16, 16, 64, total);
    }
    // x3c = dwconv3x3(p3[:, :8], w3, b3) -> (8,8,16,16)
    {
        int total = NB * 8 * 16 * 16;
        dwconv_kernel<<<(total + 255) / 256, 256, 0, stream>>>(p3, w3, b3, x3c, 16, 8, 16, total);
    }
    // p4 = maxpool4(p3[:, 8:16]) -> (8,8,4,4)
    {
        int total = NB * 8 * 4 * 4;
        pool4_kernel<<<(total + 255) / 256, 256, 0, stream>>>(p3, p4, 16, 8, 8, 16, total);
    }
    // x4c = dwconv3x3(p4, w4, b4) -> (8,8,4,4)
    {
        int total = NB * 8 * 4 * 4;
        dwconv_kernel<<<(total + 255) / 256, 256, 0, stream>>>(p4, w4, b4, x4c, 8, 8, 4, total);
    }
    // fused main
    {
        int total = NB * NH * NW;  // 524288 pixels
        fused_main<<<total / 256, 256, 0, stream>>>(x, w1, b1, x2c, x3c, x4c, wa, ba, out);
    }
}

// Round 4
// 451.890 us; speedup vs baseline: 1.2171x; 1.2171x over previous
//
#include <hip/hip_runtime.h>
#include <math.h>

// Problem constants: x (8, 64, 256, 256) fp32
#define NB 8
#define NC 64
#define NH 256
#define NW 256

typedef short short8 __attribute__((ext_vector_type(8)));
typedef float f32x4 __attribute__((ext_vector_type(4)));

// ---------------------------------------------------------------------------
// Generic 4x4 max-pool (stride 4). Input: channels [cOff, cOff+C) of an
// inC-channel HxH tensor. Output: (B, C, H/4, H/4) contiguous.
// ---------------------------------------------------------------------------
__global__ void pool4_kernel(const float* __restrict__ in, float* __restrict__ out,
                             int inC, int cOff, int C, int H, int total) {
    int idx = blockIdx.x * blockDim.x + threadIdx.x;
    if (idx >= total) return;
    int Ho = H >> 2;
    int pw = idx % Ho;
    int t  = idx / Ho;
    int ph = t % Ho;  t /= Ho;
    int c  = t % C;
    int b  = t / C;
    const float* src = in + (((size_t)b * inC + cOff + c) * H + ph * 4) * H + pw * 4;
    float m = -INFINITY;
#pragma unroll
    for (int i = 0; i < 4; ++i) {
        float4 v = *reinterpret_cast<const float4*>(src + (size_t)i * H);
        m = fmaxf(m, fmaxf(fmaxf(v.x, v.y), fmaxf(v.z, v.w)));
    }
    out[idx] = m;
}

// ---------------------------------------------------------------------------
// Generic depthwise 3x3, pad=1. Input: first C channels of an inC-channel
// HxH tensor. Output: (B, C, H, H) contiguous.
// ---------------------------------------------------------------------------
__global__ void dwconv_kernel(const float* __restrict__ in, const float* __restrict__ wgt,
                              const float* __restrict__ bias, float* __restrict__ out,
                              int inC, int C, int H, int total) {
    int idx = blockIdx.x * blockDim.x + threadIdx.x;
    if (idx >= total) return;
    int xw = idx % H;
    int t  = idx / H;
    int yh = t % H;  t /= H;
    int c  = t % C;
    int b  = t / C;
    const float* src = in + ((size_t)b * inC + c) * (size_t)(H * H);
    float acc = bias[c];
#pragma unroll
    for (int dy = -1; dy <= 1; ++dy) {
        int yy = yh + dy;
        if (yy < 0 || yy >= H) continue;
#pragma unroll
        for (int dx = -1; dx <= 1; ++dx) {
            int xx = xw + dx;
            if (xx < 0 || xx >= H) continue;
            acc += src[(size_t)yy * H + xx] * wgt[c * 9 + (dy + 1) * 3 + (dx + 1)];
        }
    }
    out[idx] = acc;
}

// f32 -> bf16 round-to-nearest-even (finite inputs)
__device__ __forceinline__ unsigned short f2bf(float f) {
    unsigned int u = __float_as_uint(f);
    u += 0x7FFFu + ((u >> 16) & 1u);
    return (unsigned short)(u >> 16);
}

// Pack 8 floats -> 8 bf16 (int4) and write to swizzled LDS slot.
// Layout: row-major [row][64] bf16, 8-elem group g stored at (g ^ (row&7)).
__device__ __forceinline__ void write_chunk8(unsigned short* lds, int row, int g,
                                             const float* v) {
    int4 pk;
    pk.x = (unsigned)f2bf(v[0]) | ((unsigned)f2bf(v[1]) << 16);
    pk.y = (unsigned)f2bf(v[2]) | ((unsigned)f2bf(v[3]) << 16);
    pk.z = (unsigned)f2bf(v[4]) | ((unsigned)f2bf(v[5]) << 16);
    pk.w = (unsigned)f2bf(v[6]) | ((unsigned)f2bf(v[7]) << 16);
    *reinterpret_cast<int4*>(&lds[row * 64 + ((g ^ (row & 7)) << 3)]) = pk;
}

// ---------------------------------------------------------------------------
// Fused main kernel. Block = one (b,h) row of 256 pixels, 256 threads (4 waves).
// Phase 1: thread t computes cat[64] for pixel w=t (dwconv ch0-31 + pyramid
//          gathers), packs to bf16, writes LDS cat_lds[px][ch] (XOR-swizzled).
//          wa (64x64) is also staged to LDS as bf16.
// Phase 2: wave wv computes D[64 out][64 px] = wa x cat^T for px block wv*64
//          via 32x mfma_f32_16x16x32_bf16, bias in C-init; epilogue does
//          exact GELU * x and coalesced stores.
// ---------------------------------------------------------------------------
__launch_bounds__(256)
__global__ void fused_main(const float* __restrict__ x,
                           const float* __restrict__ w1, const float* __restrict__ b1,
                           const float* __restrict__ x2c,
                           const float* __restrict__ x3c,
                           const float* __restrict__ x4c,
                           const float* __restrict__ wa, const float* __restrict__ ba,
                           float* __restrict__ out) {
    __shared__ __align__(16) unsigned short cat_lds[256 * 64];  // 32 KB
    __shared__ __align__(16) unsigned short wa_lds[64 * 64];    //  8 KB

    const int tid = threadIdx.x;
    const int h = blockIdx.x & 255;
    const int b = blockIdx.x >> 8;
    const size_t plane = (size_t)NH * NW;

    // ---- stage wa -> LDS (bf16, swizzled). 256 threads x 16 elems ----
    {
        int r = tid >> 2;
        int g0 = (tid & 3) * 2;
#pragma unroll
        for (int gg = 0; gg < 2; ++gg) {
            int g = g0 + gg;
            const float* src = wa + r * 64 + g * 8;
            float v[8];
#pragma unroll
            for (int j = 0; j < 8; ++j) v[j] = src[j];
            write_chunk8(wa_lds, r, g, v);
        }
    }

    // ---- phase 1: cat for pixel w = tid ----
    const int w = tid;
    const float* xb = x + (size_t)b * NC * plane;
    {
        bool hv0 = (h > 0), hv2 = (h < NH - 1);
        bool wv0 = (w > 0), wv2 = (w < NW - 1);
        int r0 = (h - 1) * NW + w, r1 = h * NW + w, r2 = (h + 1) * NW + w;
        float v[8];
#pragma unroll
        for (int g = 0; g < 4; ++g) {
#pragma unroll
            for (int j = 0; j < 8; ++j) {
                int c = g * 8 + j;
                const float* src = xb + (size_t)c * plane;
                const float* wc = w1 + c * 9;
                float acc = b1[c];
                if (hv0) {
                    if (wv0) acc += src[r0 - 1] * wc[0];
                    acc += src[r0] * wc[1];
                    if (wv2) acc += src[r0 + 1] * wc[2];
                }
                {
                    if (wv0) acc += src[r1 - 1] * wc[3];
                    acc += src[r1] * wc[4];
                    if (wv2) acc += src[r1 + 1] * wc[5];
                }
                if (hv2) {
                    if (wv0) acc += src[r2 - 1] * wc[6];
                    acc += src[r2] * wc[7];
                    if (wv2) acc += src[r2 + 1] * wc[8];
                }
                v[j] = acc;
            }
            write_chunk8(cat_lds, w, g, v);
        }
        // pyramid gathers
        int h4 = h >> 2, w4 = w >> 2;
#pragma unroll
        for (int j = 0; j < 8; ++j)
            v[j] = x2c[(((size_t)b * 16 + j) * 64 + h4) * 64 + w4];
        write_chunk8(cat_lds, w, 4, v);
#pragma unroll
        for (int j = 0; j < 8; ++j)
            v[j] = x2c[(((size_t)b * 16 + 8 + j) * 64 + h4) * 64 + w4];
        write_chunk8(cat_lds, w, 5, v);
        int h16 = h >> 4, w16 = w >> 4;
#pragma unroll
        for (int j = 0; j < 8; ++j)
            v[j] = x3c[(((size_t)b * 8 + j) * 16 + h16) * 16 + w16];
        write_chunk8(cat_lds, w, 6, v);
        int h64 = h >> 6, w64 = w >> 6;
#pragma unroll
        for (int j = 0; j < 8; ++j)
            v[j] = x4c[(((size_t)b * 8 + j) * 4 + h64) * 4 + w64];
        write_chunk8(cat_lds, w, 7, v);
    }

    __syncthreads();

    // ---- phase 2: MFMA GEMM D[64 out][64 px] = wa x cat^T per wave ----
    const int lane = tid & 63;
    const int wv = tid >> 6;
    const int lr = lane & 15;    // column selector (px / A-row)
    const int lk = lane >> 4;    // 0..3
    const int pxb = wv * 64;

    // B fragments: B[k][n] = cat^T[ch][px] = cat_lds[px][ch], 8 contiguous ch
    short8 bfrag[4][2];
#pragma unroll
    for (int nt = 0; nt < 4; ++nt) {
        int px = pxb + nt * 16 + lr;
#pragma unroll
        for (int kt = 0; kt < 2; ++kt) {
            int g = kt * 4 + lk;
            bfrag[nt][kt] = *reinterpret_cast<const short8*>(
                &cat_lds[px * 64 + ((g ^ (px & 7)) << 3)]);
        }
    }

    const size_t outbase = (size_t)(b * 64) * plane + (size_t)h * NW;

#pragma unroll
    for (int mt = 0; mt < 4; ++mt) {
        // A fragments: A[m][k] = wa[mt*16 + (lane&15)][kt*32 + lk*8 + j]
        short8 afrag[2];
        int row = mt * 16 + lr;
#pragma unroll
        for (int kt = 0; kt < 2; ++kt) {
            int g = kt * 4 + lk;
            afrag[kt] = *reinterpret_cast<const short8*>(
                &wa_lds[row * 64 + ((g ^ (row & 7)) << 3)]);
        }
        // accumulators, bias in C-init: acc[nt][r] -> out ch mt*16 + lk*4 + r
        int obase = mt * 16 + lk * 4;
        float bs0 = ba[obase], bs1 = ba[obase + 1], bs2 = ba[obase + 2], bs3 = ba[obase + 3];
        f32x4 acc[4];
#pragma unroll
        for (int nt = 0; nt < 4; ++nt) {
            acc[nt][0] = bs0; acc[nt][1] = bs1; acc[nt][2] = bs2; acc[nt][3] = bs3;
        }
#pragma unroll
        for (int nt = 0; nt < 4; ++nt)
#pragma unroll
            for (int kt = 0; kt < 2; ++kt)
                acc[nt] = __builtin_amdgcn_mfma_f32_16x16x32_bf16(
                    afrag[kt], bfrag[nt][kt], acc[nt], 0, 0, 0);

        // epilogue: D[o][px], o = obase + r, px = pxb + nt*16 + lr
#pragma unroll
        for (int nt = 0; nt < 4; ++nt) {
            int pxg = pxb + nt * 16 + lr;
#pragma unroll
            for (int r = 0; r < 4; ++r) {
                int o = obase + r;
                size_t off = outbase + (size_t)o * plane + pxg;
                float a = acc[nt][r];
                float gl = 0.5f * a * (1.0f + erff(a * 0.70710678118654752f));
                out[off] = gl * x[off];
            }
        }
    }
}

extern "C" void kernel_launch(void* const* d_in, const int* in_sizes, int n_in,
                              void* d_out, int out_size, void* d_ws, size_t ws_size,
                              hipStream_t stream) {
    const float* x  = (const float*)d_in[0];
    const float* w1 = (const float*)d_in[1];
    const float* b1 = (const float*)d_in[2];
    const float* w2 = (const float*)d_in[3];
    const float* b2 = (const float*)d_in[4];
    const float* w3 = (const float*)d_in[5];
    const float* b3 = (const float*)d_in[6];
    const float* w4 = (const float*)d_in[7];
    const float* b4 = (const float*)d_in[8];
    const float* wa = (const float*)d_in[9];
    const float* ba = (const float*)d_in[10];
    float* out = (float*)d_out;

    // Workspace layout (floats)
    float* ws   = (float*)d_ws;
    float* p2   = ws;                       // 8*32*64*64 = 1048576
    float* x2c  = p2  + 1048576;            // 8*16*64*64 = 524288
    float* p3   = x2c + 524288;             // 8*16*16*16 = 32768
    float* x3c  = p3  + 32768;              // 8*8*16*16  = 16384
    float* p4   = x3c + 16384;              // 8*8*4*4    = 1024
    float* x4c  = p4  + 1024;               // 8*8*4*4    = 1024

    {   // p2 = maxpool4(x[:, 32:64]) -> (8,32,64,64)
        int total = NB * 32 * 64 * 64;
        pool4_kernel<<<(total + 255) / 256, 256, 0, stream>>>(x, p2, 64, 32, 32, 256, total);
    }
    {   // x2c = dwconv3x3(p2[:, :16]) -> (8,16,64,64)
        int total = NB * 16 * 64 * 64;
        dwconv_kernel<<<(total + 255) / 256, 256, 0, stream>>>(p2, w2, b2, x2c, 32, 16, 64, total);
    }
    {   // p3 = maxpool4(p2[:, 16:32]) -> (8,16,16,16)
        int total = NB * 16 * 16 * 16;
        pool4_kernel<<<(total + 255) / 256, 256, 0, stream>>>(p2, p3, 32, 16, 16, 64, total);
    }
    {   // x3c = dwconv3x3(p3[:, :8]) -> (8,8,16,16)
        int total = NB * 8 * 16 * 16;
        dwconv_kernel<<<(total + 255) / 256, 256, 0, stream>>>(p3, w3, b3, x3c, 16, 8, 16, total);
    }
    {   // p4 = maxpool4(p3[:, 8:16]) -> (8,8,4,4)
        int total = NB * 8 * 4 * 4;
        pool4_kernel<<<(total + 255) / 256, 256, 0, stream>>>(p3, p4, 16, 8, 8, 16, total);
    }
    {   // x4c = dwconv3x3(p4) -> (8,8,4,4)
        int total = NB * 8 * 4 * 4;
        dwconv_kernel<<<(total + 255) / 256, 256, 0, stream>>>(p4, w4, b4, x4c, 8, 8, 4, total);
    }
    {   // fused main: one block per (b,h) row
        fused_main<<<NB * NH, 256, 0, stream>>>(x, w1, b1, x2c, x3c, x4c, wa, ba, out);
    }
}

// Round 6
// 294.971 us; speedup vs baseline: 1.8646x; 1.5320x over previous
//
#include <hip/hip_runtime.h>
#include <math.h>

// Problem constants: x (8, 64, 256, 256) fp32
#define NB 8
#define NC 64
#define NH 256
#define NW 256

typedef short short8 __attribute__((ext_vector_type(8)));
typedef float f32x4 __attribute__((ext_vector_type(4)));

// f32 -> bf16 round-to-nearest-even (finite inputs)
__device__ __forceinline__ unsigned short f2bf(float f) {
    unsigned int u = __float_as_uint(f);
    u += 0x7FFFu + ((u >> 16) & 1u);
    return (unsigned short)(u >> 16);
}

// LDS granule swizzle: 16B granule (8 bf16 ch) g of pixel px lives at slot
// SLOT(px,g). Spreads banks for (a) phase-1 writes px=4q+i, (b) MFMA reads
// px=C+lr. Bijective in g for fixed px.
__device__ __forceinline__ int slot_of(int px, int g) {
    return g ^ (px & 7) ^ ((px >> 3) & 7);
}

// ---------------------------------------------------------------------------
// Pyramid kernel: entire maxpool/dwconv chain in one launch.
// After the channel split everything is per-channel (depthwise):
//   c in [0,16):  x2c[b,c]    = dwconv64(pool4(x[b,32+c]))
//   c in [16,24): x3c[b,c-16] = dwconv16(pool4(pool4(x[b,32+c])))
//   c in [24,32): x4c[b,c-24] = dwconv4 (pool4^3(x[b,32+c]))
// One block per (b,c); 256 threads.
// ---------------------------------------------------------------------------
__launch_bounds__(256)
__global__ void pyramid_kernel(const float* __restrict__ x,
                               const float* __restrict__ w2, const float* __restrict__ b2,
                               const float* __restrict__ w3, const float* __restrict__ b3,
                               const float* __restrict__ w4, const float* __restrict__ b4,
                               float* __restrict__ x2c, float* __restrict__ x3c,
                               float* __restrict__ x4c) {
    __shared__ float pl[64 * 65];   // 64x64 pooled plane (pad 65)
    __shared__ float pl2[16 * 17];  // 16x16
    __shared__ float pl3[16];       // 4x4

    const int tid = threadIdx.x;
    const int c = blockIdx.x & 31;
    const int b = blockIdx.x >> 5;
    const size_t plane = (size_t)NH * NW;
    const float* src = x + ((size_t)(b * 64 + 32 + c)) * plane;

    // pool4: 256x256 -> 64x64
#pragma unroll
    for (int i = 0; i < 16; ++i) {
        int o = tid + 256 * i;
        int pw = o & 63, ph = o >> 6;
        const float* s2 = src + (size_t)(ph * 4) * NW + pw * 4;
        float m = -INFINITY;
#pragma unroll
        for (int r = 0; r < 4; ++r) {
            float4 v = *reinterpret_cast<const float4*>(s2 + (size_t)r * NW);
            m = fmaxf(m, fmaxf(fmaxf(v.x, v.y), fmaxf(v.z, v.w)));
        }
        pl[ph * 65 + pw] = m;
    }
    __syncthreads();

    if (c < 16) {
        // dwconv 64x64 -> x2c[b,c]
        float* dst = x2c + ((size_t)(b * 16 + c)) * 4096;
        const float* wc = w2 + c * 9;
        float bb = b2[c];
#pragma unroll
        for (int i = 0; i < 16; ++i) {
            int o = tid + 256 * i;
            int pw = o & 63, ph = o >> 6;
            float acc = bb;
#pragma unroll
            for (int dy = -1; dy <= 1; ++dy) {
                int yy = ph + dy;
                if (yy < 0 || yy >= 64) continue;
#pragma unroll
                for (int dx = -1; dx <= 1; ++dx) {
                    int xx = pw + dx;
                    if (xx < 0 || xx >= 64) continue;
                    acc += pl[yy * 65 + xx] * wc[(dy + 1) * 3 + (dx + 1)];
                }
            }
            dst[o] = acc;
        }
    } else {
        // pool4: 64x64 -> 16x16
        {
            int pw = tid & 15, ph = tid >> 4;   // tid < 256 covers all
            float m = -INFINITY;
#pragma unroll
            for (int r = 0; r < 4; ++r)
#pragma unroll
                for (int cc = 0; cc < 4; ++cc)
                    m = fmaxf(m, pl[(ph * 4 + r) * 65 + pw * 4 + cc]);
            pl2[ph * 17 + pw] = m;
        }
        __syncthreads();
        if (c < 24) {
            // dwconv 16x16 -> x3c[b, c-16]
            int pw = tid & 15, ph = tid >> 4;
            const float* wc = w3 + (c - 16) * 9;
            float acc = b3[c - 16];
#pragma unroll
            for (int dy = -1; dy <= 1; ++dy) {
                int yy = ph + dy;
                if (yy < 0 || yy >= 16) continue;
#pragma unroll
                for (int dx = -1; dx <= 1; ++dx) {
                    int xx = pw + dx;
                    if (xx < 0 || xx >= 16) continue;
                    acc += pl2[yy * 17 + xx] * wc[(dy + 1) * 3 + (dx + 1)];
                }
            }
            x3c[((size_t)(b * 8 + (c - 16))) * 256 + tid] = acc;
        } else {
            // pool4: 16x16 -> 4x4
            if (tid < 16) {
                int pw = tid & 3, ph = tid >> 2;
                float m = -INFINITY;
#pragma unroll
                for (int r = 0; r < 4; ++r)
#pragma unroll
                    for (int cc = 0; cc < 4; ++cc)
                        m = fmaxf(m, pl2[(ph * 4 + r) * 17 + pw * 4 + cc]);
                pl3[ph * 4 + pw] = m;
            }
            __syncthreads();
            if (tid < 16) {
                int pw = tid & 3, ph = tid >> 2;
                const float* wc = w4 + (c - 24) * 9;
                float acc = b4[c - 24];
#pragma unroll
                for (int dy = -1; dy <= 1; ++dy) {
                    int yy = ph + dy;
                    if (yy < 0 || yy >= 4) continue;
#pragma unroll
                    for (int dx = -1; dx <= 1; ++dx) {
                        int xx = pw + dx;
                        if (xx < 0 || xx >= 4) continue;
                        acc += pl3[yy * 4 + xx] * wc[(dy + 1) * 3 + (dx + 1)];
                    }
                }
                x4c[((size_t)(b * 8 + (c - 24))) * 16 + tid] = acc;
            }
        }
    }
}

// ---------------------------------------------------------------------------
// Fused main. Block = one (b,h) row of 256 px, 256 threads (4 waves).
// Phase 1 (vectorized): wave cg owns conv channels cg*8..+8; lane q owns px
//   quad 4q..4q+3. 3 rows x 8ch float4 loads; w-neighbors via __shfl.
//   Pyramid gathers: quad-uniform (w4=q), 8 scalar loads per thread.
//   Results packed bf16 into cat_lds granules [px][slot(px,g)].
// Phase 2: per-wave MFMA D[64ch][64px] = wa x cat^T (bias in C-init).
// Epilogue: per mt, GELU -> 16KB LDS buffer (double-buffered, 1 barrier/mt),
//   then fully-coalesced float4 gating (x load, out store).
// ---------------------------------------------------------------------------
__launch_bounds__(256)
__global__ void fused_main(const float* __restrict__ x,
                           const float* __restrict__ w1, const float* __restrict__ b1,
                           const float* __restrict__ x2c,
                           const float* __restrict__ x3c,
                           const float* __restrict__ x4c,
                           const float* __restrict__ wa, const float* __restrict__ ba,
                           float* __restrict__ out) {
    __shared__ __align__(16) unsigned short cat_lds[256 * 64];  // 32 KB (reused as 2x16KB f32)
    __shared__ __align__(16) unsigned short wa_lds[64 * 64];    //  8 KB

    const int tid = threadIdx.x;
    const int q = tid & 63;      // lane = pixel quad
    const int cg = tid >> 6;     // wave = channel group
    const int h = blockIdx.x & 255;
    const int b = blockIdx.x >> 8;
    const size_t plane = (size_t)NH * NW;
    const float* xb = x + (size_t)b * NC * plane;

    // ---- stage wa -> LDS (bf16, swizzled granules) ----
    {
        int r = tid >> 2;
        int g0 = (tid & 3) * 2;
#pragma unroll
        for (int gg = 0; gg < 2; ++gg) {
            int g = g0 + gg;
            const float* srcw = wa + r * 64 + g * 8;
            int4 pk;
            pk.x = (unsigned)f2bf(srcw[0]) | ((unsigned)f2bf(srcw[1]) << 16);
            pk.y = (unsigned)f2bf(srcw[2]) | ((unsigned)f2bf(srcw[3]) << 16);
            pk.z = (unsigned)f2bf(srcw[4]) | ((unsigned)f2bf(srcw[5]) << 16);
            pk.w = (unsigned)f2bf(srcw[6]) | ((unsigned)f2bf(srcw[7]) << 16);
            *reinterpret_cast<int4*>(&wa_lds[r * 64 + slot_of(r, g) * 8]) = pk;
        }
    }

    // ---- phase 1: conv (8 ch x 4 px per thread) ----
    const bool hv0 = (h > 0), hv2 = (h < NH - 1);
    const int hm = hv0 ? h - 1 : h;
    const int hp = hv2 ? h + 1 : h;
    float conv[8][4];
#pragma unroll
    for (int j = 0; j < 8; ++j) {
        const int c = cg * 8 + j;
        const float* srcc = xb + (size_t)c * plane;
        float4 a0 = *reinterpret_cast<const float4*>(srcc + (size_t)hm * NW + 4 * q);
        float4 a1 = *reinterpret_cast<const float4*>(srcc + (size_t)h  * NW + 4 * q);
        float4 a2 = *reinterpret_cast<const float4*>(srcc + (size_t)hp * NW + 4 * q);
        const float* wc = w1 + c * 9;   // wave-uniform -> SGPR
        float k0 = hv0 ? wc[0] : 0.f, k1 = hv0 ? wc[1] : 0.f, k2 = hv0 ? wc[2] : 0.f;
        float k3 = wc[3], k4 = wc[4], k5 = wc[5];
        float k6 = hv2 ? wc[6] : 0.f, k7 = hv2 ? wc[7] : 0.f, k8 = hv2 ? wc[8] : 0.f;
        float p0 = __shfl_up(a0.w, 1), p1 = __shfl_up(a1.w, 1), p2 = __shfl_up(a2.w, 1);
        float n0 = __shfl_down(a0.x, 1), n1 = __shfl_down(a1.x, 1), n2 = __shfl_down(a2.x, 1);
        if (q == 0)  { p0 = 0.f; p1 = 0.f; p2 = 0.f; }   // w=0 left pad
        if (q == 63) { n0 = 0.f; n1 = 0.f; n2 = 0.f; }   // w=255 right pad
        float r0[6] = {p0, a0.x, a0.y, a0.z, a0.w, n0};
        float r1[6] = {p1, a1.x, a1.y, a1.z, a1.w, n1};
        float r2[6] = {p2, a2.x, a2.y, a2.z, a2.w, n2};
#pragma unroll
        for (int i = 0; i < 4; ++i) {
            conv[j][i] = k0 * r0[i] + k1 * r0[i + 1] + k2 * r0[i + 2]
                       + k3 * r1[i] + k4 * r1[i + 1] + k5 * r1[i + 2]
                       + k6 * r2[i] + k7 * r2[i + 1] + k8 * r2[i + 2]
                       + b1[c];
        }
    }
    // pack conv -> granules
#pragma unroll
    for (int i = 0; i < 4; ++i) {
        int px = 4 * q + i;
        int4 pk;
        pk.x = (unsigned)f2bf(conv[0][i]) | ((unsigned)f2bf(conv[1][i]) << 16);
        pk.y = (unsigned)f2bf(conv[2][i]) | ((unsigned)f2bf(conv[3][i]) << 16);
        pk.z = (unsigned)f2bf(conv[4][i]) | ((unsigned)f2bf(conv[5][i]) << 16);
        pk.w = (unsigned)f2bf(conv[6][i]) | ((unsigned)f2bf(conv[7][i]) << 16);
        *reinterpret_cast<int4*>(&cat_lds[px * 64 + slot_of(px, cg) * 8]) = pk;
    }

    // ---- phase 1b: pyramid gathers (quad-uniform values, w4 == q) ----
    {
        float pv[8];
        const int h4 = h >> 2, h16 = h >> 4, h64 = h >> 6;
        if (cg == 0) {
#pragma unroll
            for (int j = 0; j < 8; ++j)
                pv[j] = x2c[(((size_t)b * 16 + j) * 64 + h4) * 64 + q];
        } else if (cg == 1) {
#pragma unroll
            for (int j = 0; j < 8; ++j)
                pv[j] = x2c[(((size_t)b * 16 + 8 + j) * 64 + h4) * 64 + q];
        } else if (cg == 2) {
#pragma unroll
            for (int j = 0; j < 8; ++j)
                pv[j] = x3c[(((size_t)b * 8 + j) * 16 + h16) * 16 + (q >> 2)];
        } else {
#pragma unroll
            for (int j = 0; j < 8; ++j)
                pv[j] = x4c[(((size_t)b * 8 + j) * 4 + h64) * 4 + (q >> 4)];
        }
        int4 pk;
        pk.x = (unsigned)f2bf(pv[0]) | ((unsigned)f2bf(pv[1]) << 16);
        pk.y = (unsigned)f2bf(pv[2]) | ((unsigned)f2bf(pv[3]) << 16);
        pk.z = (unsigned)f2bf(pv[4]) | ((unsigned)f2bf(pv[5]) << 16);
        pk.w = (unsigned)f2bf(pv[6]) | ((unsigned)f2bf(pv[7]) << 16);
#pragma unroll
        for (int i = 0; i < 4; ++i) {
            int px = 4 * q + i;
            *reinterpret_cast<int4*>(&cat_lds[px * 64 + slot_of(px, 4 + cg) * 8]) = pk;
        }
    }

    __syncthreads();

    // ---- phase 2: MFMA D[64ch][64px] per wave ----
    const int lane = tid & 63;
    const int lr = lane & 15;
    const int lk = lane >> 4;
    const int pxb = cg * 64;

    short8 bfrag[4][2];
#pragma unroll
    for (int nt = 0; nt < 4; ++nt) {
        int px = pxb + nt * 16 + lr;
#pragma unroll
        for (int kt = 0; kt < 2; ++kt) {
            int g = kt * 4 + lk;
            bfrag[nt][kt] = *reinterpret_cast<const short8*>(
                &cat_lds[px * 64 + slot_of(px, g) * 8]);
        }
    }
    __syncthreads();   // cat_lds now repurposed as gelu staging buffers

    const size_t outrow = (size_t)h * NW;

#pragma unroll
    for (int mt = 0; mt < 4; ++mt) {
        // A fragments from wa_lds
        short8 afrag[2];
        int row = mt * 16 + lr;
#pragma unroll
        for (int kt = 0; kt < 2; ++kt) {
            int g = kt * 4 + lk;
            afrag[kt] = *reinterpret_cast<const short8*>(
                &wa_lds[row * 64 + slot_of(row, g) * 8]);
        }
        int obase = mt * 16 + lk * 4;
        float bs0 = ba[obase], bs1 = ba[obase + 1], bs2 = ba[obase + 2], bs3 = ba[obase + 3];
        f32x4 acc[4];
#pragma unroll
        for (int nt = 0; nt < 4; ++nt) {
            acc[nt][0] = bs0; acc[nt][1] = bs1; acc[nt][2] = bs2; acc[nt][3] = bs3;
        }
#pragma unroll
        for (int nt = 0; nt < 4; ++nt)
#pragma unroll
            for (int kt = 0; kt < 2; ++kt)
                acc[nt] = __builtin_amdgcn_mfma_f32_16x16x32_bf16(
                    afrag[kt], bfrag[nt][kt], acc[nt], 0, 0, 0);

        // GELU -> LDS staging buffer (alternating halves of cat_lds)
        float* buf = reinterpret_cast<float*>(cat_lds) + (mt & 1) * 4096;
#pragma unroll
        for (int nt = 0; nt < 4; ++nt) {
            int px = pxb + nt * 16 + lr;
#pragma unroll
            for (int r = 0; r < 4; ++r) {
                float a = acc[nt][r];
                float gl = 0.5f * a * (1.0f + erff(a * 0.70710678118654752f));
                buf[(lk * 4 + r) * 256 + px] = gl;
            }
        }
        __syncthreads();

        // coalesced gating: float4 x-load, float4 store
#pragma unroll
        for (int i = 0; i < 4; ++i) {
            int t2 = tid + 256 * i;
            int chLoc = t2 >> 6;          // 0..15
            int pq = t2 & 63;             // pixel quad
            float4 gv = *reinterpret_cast<const float4*>(&buf[chLoc * 256 + pq * 4]);
            size_t off = ((size_t)(b * 64 + mt * 16 + chLoc)) * plane + outrow + pq * 4;
            float4 xv = *reinterpret_cast<const float4*>(&x[off]);
            float4 ov;
            ov.x = gv.x * xv.x; ov.y = gv.y * xv.y; ov.z = gv.z * xv.z; ov.w = gv.w * xv.w;
            *reinterpret_cast<float4*>(&out[off]) = ov;
        }
    }
}

extern "C" void kernel_launch(void* const* d_in, const int* in_sizes, int n_in,
                              void* d_out, int out_size, void* d_ws, size_t ws_size,
                              hipStream_t stream) {
    const float* x  = (const float*)d_in[0];
    const float* w1 = (const float*)d_in[1];
    const float* b1 = (const float*)d_in[2];
    const float* w2 = (const float*)d_in[3];
    const float* b2 = (const float*)d_in[4];
    const float* w3 = (const float*)d_in[5];
    const float* b3 = (const float*)d_in[6];
    const float* w4 = (const float*)d_in[7];
    const float* b4 = (const float*)d_in[8];
    const float* wa = (const float*)d_in[9];
    const float* ba = (const float*)d_in[10];
    float* out = (float*)d_out;

    // Workspace (floats): only the conv outputs are materialized now
    float* ws  = (float*)d_ws;
    float* x2c = ws;               // 8*16*64*64 = 524288
    float* x3c = x2c + 524288;     // 8*8*16*16  = 16384
    float* x4c = x3c + 16384;      // 8*8*4*4    = 1024

    // whole pyramid chain in one kernel: one block per (b, c)
    pyramid_kernel<<<NB * 32, 256, 0, stream>>>(x, w2, b2, w3, b3, w4, b4,
                                                x2c, x3c, x4c);
    // fused main: one block per (b, h) row
    fused_main<<<NB * NH, 256, 0, stream>>>(x, w1, b1, x2c, x3c, x4c, wa, ba, out);
}

// Round 7
// 282.492 us; speedup vs baseline: 1.9470x; 1.0442x over previous
//
#include <hip/hip_runtime.h>
#include <math.h>

// Problem constants: x (8, 64, 256, 256) fp32
#define NB 8
#define NC 64
#define NH 256
#define NW 256

typedef short short8 __attribute__((ext_vector_type(8)));
typedef float f32x4 __attribute__((ext_vector_type(4)));

// f32 -> bf16 round-to-nearest-even (finite inputs)
__device__ __forceinline__ unsigned short f2bf(float f) {
    unsigned int u = __float_as_uint(f);
    u += 0x7FFFu + ((u >> 16) & 1u);
    return (unsigned short)(u >> 16);
}

// LDS granule swizzle for cat: 16B granule (8 bf16 ch) g of pixel px at slot
// SLOT(px,g). Bijective in g for fixed px; spreads phase-1 writes and MFMA reads.
__device__ __forceinline__ int slot_of(int px, int g) {
    return g ^ (px & 7) ^ ((px >> 3) & 7);
}

// ---------------------------------------------------------------------------
// Pyramid kernel: entire maxpool/dwconv chain in one launch. 1024 thr/block
// (16 waves -> latency hiding for the pool4 row loads).
//   c in [0,16):  x2c[b,c]    = dwconv64(pool4(x[b,32+c]))
//   c in [16,24): x3c[b,c-16] = dwconv16(pool4^2(x[b,32+c]))
//   c in [24,32): x4c[b,c-24] = dwconv4 (pool4^3(x[b,32+c]))
// One block per (b,c).
// ---------------------------------------------------------------------------
__launch_bounds__(1024)
__global__ void pyramid_kernel(const float* __restrict__ x,
                               const float* __restrict__ w2, const float* __restrict__ b2,
                               const float* __restrict__ w3, const float* __restrict__ b3,
                               const float* __restrict__ w4, const float* __restrict__ b4,
                               float* __restrict__ x2c, float* __restrict__ x3c,
                               float* __restrict__ x4c) {
    __shared__ float pl[64 * 65];   // 64x64 pooled plane (pad 65)
    __shared__ float pl2[16 * 17];  // 16x16
    __shared__ float pl3[16];       // 4x4

    const int tid = threadIdx.x;
    const int c = blockIdx.x & 31;
    const int b = blockIdx.x >> 5;
    const size_t plane = (size_t)NH * NW;
    const float* src = x + ((size_t)(b * 64 + 32 + c)) * plane;

    // pool4: 256x256 -> 64x64  (4096 outputs, 1024 threads x 4)
#pragma unroll
    for (int i = 0; i < 4; ++i) {
        int o = tid + 1024 * i;
        int pw = o & 63, ph = o >> 6;
        const float* s2 = src + (size_t)(ph * 4) * NW + pw * 4;
        float m = -INFINITY;
#pragma unroll
        for (int r = 0; r < 4; ++r) {
            float4 v = *reinterpret_cast<const float4*>(s2 + (size_t)r * NW);
            m = fmaxf(m, fmaxf(fmaxf(v.x, v.y), fmaxf(v.z, v.w)));
        }
        pl[ph * 65 + pw] = m;
    }
    __syncthreads();

    if (c < 16) {
        // dwconv 64x64 -> x2c[b,c]
        float* dst = x2c + ((size_t)(b * 16 + c)) * 4096;
        const float* wc = w2 + c * 9;
        float bb = b2[c];
#pragma unroll
        for (int i = 0; i < 4; ++i) {
            int o = tid + 1024 * i;
            int pw = o & 63, ph = o >> 6;
            float acc = bb;
#pragma unroll
            for (int dy = -1; dy <= 1; ++dy) {
                int yy = ph + dy;
                if (yy < 0 || yy >= 64) continue;
#pragma unroll
                for (int dx = -1; dx <= 1; ++dx) {
                    int xx = pw + dx;
                    if (xx < 0 || xx >= 64) continue;
                    acc += pl[yy * 65 + xx] * wc[(dy + 1) * 3 + (dx + 1)];
                }
            }
            dst[o] = acc;
        }
    } else {
        // pool4: 64x64 -> 16x16
        if (tid < 256) {
            int pw = tid & 15, ph = tid >> 4;
            float m = -INFINITY;
#pragma unroll
            for (int r = 0; r < 4; ++r)
#pragma unroll
                for (int cc = 0; cc < 4; ++cc)
                    m = fmaxf(m, pl[(ph * 4 + r) * 65 + pw * 4 + cc]);
            pl2[ph * 17 + pw] = m;
        }
        __syncthreads();
        if (c < 24) {
            // dwconv 16x16 -> x3c[b, c-16]
            if (tid < 256) {
                int pw = tid & 15, ph = tid >> 4;
                const float* wc = w3 + (c - 16) * 9;
                float acc = b3[c - 16];
#pragma unroll
                for (int dy = -1; dy <= 1; ++dy) {
                    int yy = ph + dy;
                    if (yy < 0 || yy >= 16) continue;
#pragma unroll
                    for (int dx = -1; dx <= 1; ++dx) {
                        int xx = pw + dx;
                        if (xx < 0 || xx >= 16) continue;
                        acc += pl2[yy * 17 + xx] * wc[(dy + 1) * 3 + (dx + 1)];
                    }
                }
                x3c[((size_t)(b * 8 + (c - 16))) * 256 + tid] = acc;
            }
        } else {
            // pool4: 16x16 -> 4x4
            if (tid < 16) {
                int pw = tid & 3, ph = tid >> 2;
                float m = -INFINITY;
#pragma unroll
                for (int r = 0; r < 4; ++r)
#pragma unroll
                    for (int cc = 0; cc < 4; ++cc)
                        m = fmaxf(m, pl2[(ph * 4 + r) * 17 + pw * 4 + cc]);
                pl3[ph * 4 + pw] = m;
            }
            __syncthreads();
            if (tid < 16) {
                int pw = tid & 3, ph = tid >> 2;
                const float* wc = w4 + (c - 24) * 9;
                float acc = b4[c - 24];
#pragma unroll
                for (int dy = -1; dy <= 1; ++dy) {
                    int yy = ph + dy;
                    if (yy < 0 || yy >= 4) continue;
#pragma unroll
                    for (int dx = -1; dx <= 1; ++dx) {
                        int xx = pw + dx;
                        if (xx < 0 || xx >= 4) continue;
                        acc += pl3[yy * 4 + xx] * wc[(dy + 1) * 3 + (dx + 1)];
                    }
                }
                x4c[((size_t)(b * 8 + (c - 24))) * 16 + tid] = acc;
            }
        }
    }
}

// ---------------------------------------------------------------------------
// Fused main. Block = one (b,h) row of 256 px, 256 threads (4 waves).
// XCD remap: b = blk&7, h = blk>>3  -> each XCD owns one batch image with
//   ascending h, so h+-1 conv row re-reads hit that XCD's L2.
// Phase 1: pyramid gathers issued first (latency overlap), then conv
//   (wave cg = 8 channels, lane q = 4-px quad, float4 + shfl), packed bf16
//   into cat_lds granules.
// Phase 2: per-wave MFMA D[64ch][64px] = wa x cat^T (bias in C-init).
// Epilogue: pipelined; x gating loads for mt+1 issued right after the
//   barrier, consumed one round later. GELU staging buffer XOR-swizzled
//   (row*256 + (px ^ ((row&7)<<2))) -> <=2-way on write, clean float4 read.
// ---------------------------------------------------------------------------
__launch_bounds__(256)
__global__ void fused_main(const float* __restrict__ x,
                           const float* __restrict__ w1, const float* __restrict__ b1,
                           const float* __restrict__ x2c,
                           const float* __restrict__ x3c,
                           const float* __restrict__ x4c,
                           const float* __restrict__ wa, const float* __restrict__ ba,
                           float* __restrict__ out) {
    __shared__ __align__(16) unsigned short cat_lds[256 * 64];  // 32 KB (reused as 2x16KB f32)
    __shared__ __align__(16) unsigned short wa_lds[64 * 64];    //  8 KB

    const int tid = threadIdx.x;
    const int q = tid & 63;      // lane = pixel quad
    const int cg = tid >> 6;     // wave = channel group
    const int blk = blockIdx.x;
    const int b = blk & 7;       // XCD-local image
    const int h = blk >> 3;
    const size_t plane = (size_t)NH * NW;
    const float* xb = x + (size_t)b * NC * plane;

    // ---- stage wa -> LDS (bf16, swizzled granules) ----
    {
        int r = tid >> 2;
        int g0 = (tid & 3) * 2;
#pragma unroll
        for (int gg = 0; gg < 2; ++gg) {
            int g = g0 + gg;
            const float* srcw = wa + r * 64 + g * 8;
            int4 pk;
            pk.x = (unsigned)f2bf(srcw[0]) | ((unsigned)f2bf(srcw[1]) << 16);
            pk.y = (unsigned)f2bf(srcw[2]) | ((unsigned)f2bf(srcw[3]) << 16);
            pk.z = (unsigned)f2bf(srcw[4]) | ((unsigned)f2bf(srcw[5]) << 16);
            pk.w = (unsigned)f2bf(srcw[6]) | ((unsigned)f2bf(srcw[7]) << 16);
            *reinterpret_cast<int4*>(&wa_lds[r * 64 + slot_of(r, g) * 8]) = pk;
        }
    }

    // ---- phase 1a: pyramid gathers issued EARLY (overlap with conv) ----
    float pv[8];
    {
        const int h4 = h >> 2, h16 = h >> 4, h64 = h >> 6;
        if (cg == 0) {
#pragma unroll
            for (int j = 0; j < 8; ++j)
                pv[j] = x2c[(((size_t)b * 16 + j) * 64 + h4) * 64 + q];
        } else if (cg == 1) {
#pragma unroll
            for (int j = 0; j < 8; ++j)
                pv[j] = x2c[(((size_t)b * 16 + 8 + j) * 64 + h4) * 64 + q];
        } else if (cg == 2) {
#pragma unroll
            for (int j = 0; j < 8; ++j)
                pv[j] = x3c[(((size_t)b * 8 + j) * 16 + h16) * 16 + (q >> 2)];
        } else {
#pragma unroll
            for (int j = 0; j < 8; ++j)
                pv[j] = x4c[(((size_t)b * 8 + j) * 4 + h64) * 4 + (q >> 4)];
        }
    }

    // ---- phase 1b: conv (8 ch x 4 px per thread) ----
    const bool hv0 = (h > 0), hv2 = (h < NH - 1);
    const int hm = hv0 ? h - 1 : h;
    const int hp = hv2 ? h + 1 : h;
    float conv[8][4];
#pragma unroll
    for (int j = 0; j < 8; ++j) {
        const int c = cg * 8 + j;
        const float* srcc = xb + (size_t)c * plane;
        float4 a0 = *reinterpret_cast<const float4*>(srcc + (size_t)hm * NW + 4 * q);
        float4 a1 = *reinterpret_cast<const float4*>(srcc + (size_t)h  * NW + 4 * q);
        float4 a2 = *reinterpret_cast<const float4*>(srcc + (size_t)hp * NW + 4 * q);
        const float* wc = w1 + c * 9;   // wave-uniform -> SGPR
        float k0 = hv0 ? wc[0] : 0.f, k1 = hv0 ? wc[1] : 0.f, k2 = hv0 ? wc[2] : 0.f;
        float k3 = wc[3], k4 = wc[4], k5 = wc[5];
        float k6 = hv2 ? wc[6] : 0.f, k7 = hv2 ? wc[7] : 0.f, k8 = hv2 ? wc[8] : 0.f;
        float p0 = __shfl_up(a0.w, 1), p1 = __shfl_up(a1.w, 1), p2 = __shfl_up(a2.w, 1);
        float n0 = __shfl_down(a0.x, 1), n1 = __shfl_down(a1.x, 1), n2 = __shfl_down(a2.x, 1);
        if (q == 0)  { p0 = 0.f; p1 = 0.f; p2 = 0.f; }   // w=0 left pad
        if (q == 63) { n0 = 0.f; n1 = 0.f; n2 = 0.f; }   // w=255 right pad
        float r0[6] = {p0, a0.x, a0.y, a0.z, a0.w, n0};
        float r1[6] = {p1, a1.x, a1.y, a1.z, a1.w, n1};
        float r2[6] = {p2, a2.x, a2.y, a2.z, a2.w, n2};
#pragma unroll
        for (int i = 0; i < 4; ++i) {
            conv[j][i] = k0 * r0[i] + k1 * r0[i + 1] + k2 * r0[i + 2]
                       + k3 * r1[i] + k4 * r1[i + 1] + k5 * r1[i + 2]
                       + k6 * r2[i] + k7 * r2[i + 1] + k8 * r2[i + 2]
                       + b1[c];
        }
    }
    // pack conv -> granules
#pragma unroll
    for (int i = 0; i < 4; ++i) {
        int px = 4 * q + i;
        int4 pk;
        pk.x = (unsigned)f2bf(conv[0][i]) | ((unsigned)f2bf(conv[1][i]) << 16);
        pk.y = (unsigned)f2bf(conv[2][i]) | ((unsigned)f2bf(conv[3][i]) << 16);
        pk.z = (unsigned)f2bf(conv[4][i]) | ((unsigned)f2bf(conv[5][i]) << 16);
        pk.w = (unsigned)f2bf(conv[6][i]) | ((unsigned)f2bf(conv[7][i]) << 16);
        *reinterpret_cast<int4*>(&cat_lds[px * 64 + slot_of(px, cg) * 8]) = pk;
    }
    // pack pyramid granule (quad-uniform value)
    {
        int4 pk;
        pk.x = (unsigned)f2bf(pv[0]) | ((unsigned)f2bf(pv[1]) << 16);
        pk.y = (unsigned)f2bf(pv[2]) | ((unsigned)f2bf(pv[3]) << 16);
        pk.z = (unsigned)f2bf(pv[4]) | ((unsigned)f2bf(pv[5]) << 16);
        pk.w = (unsigned)f2bf(pv[6]) | ((unsigned)f2bf(pv[7]) << 16);
#pragma unroll
        for (int i = 0; i < 4; ++i) {
            int px = 4 * q + i;
            *reinterpret_cast<int4*>(&cat_lds[px * 64 + slot_of(px, 4 + cg) * 8]) = pk;
        }
    }

    __syncthreads();

    // ---- phase 2: MFMA D[64ch][64px] per wave ----
    const int lane = tid & 63;
    const int lr = lane & 15;
    const int lk = lane >> 4;
    const int pxb = cg * 64;

    short8 bfrag[4][2];
#pragma unroll
    for (int nt = 0; nt < 4; ++nt) {
        int px = pxb + nt * 16 + lr;
#pragma unroll
        for (int kt = 0; kt < 2; ++kt) {
            int g = kt * 4 + lk;
            bfrag[nt][kt] = *reinterpret_cast<const short8*>(
                &cat_lds[px * 64 + slot_of(px, g) * 8]);
        }
    }
    __syncthreads();   // cat_lds now repurposed as gelu staging buffers

    const size_t outrow = (size_t)h * NW;
    // gating addresses: chLoc = cg + 4i, pixel quad q
    size_t goff[4];
#pragma unroll
    for (int i = 0; i < 4; ++i)
        goff[i] = ((size_t)(b * 64 + cg + 4 * i)) * plane + outrow + q * 4;

    // prefetch x for mt=0
    float4 xcur[4], xnxt[4];
#pragma unroll
    for (int i = 0; i < 4; ++i)
        xcur[i] = *reinterpret_cast<const float4*>(&x[goff[i]]);

#pragma unroll
    for (int mt = 0; mt < 4; ++mt) {
        // A fragments from wa_lds
        short8 afrag[2];
        int row = mt * 16 + lr;
#pragma unroll
        for (int kt = 0; kt < 2; ++kt) {
            int g = kt * 4 + lk;
            afrag[kt] = *reinterpret_cast<const short8*>(
                &wa_lds[row * 64 + slot_of(row, g) * 8]);
        }
        int obase = mt * 16 + lk * 4;
        float bs0 = ba[obase], bs1 = ba[obase + 1], bs2 = ba[obase + 2], bs3 = ba[obase + 3];
        f32x4 acc[4];
#pragma unroll
        for (int nt = 0; nt < 4; ++nt) {
            acc[nt][0] = bs0; acc[nt][1] = bs1; acc[nt][2] = bs2; acc[nt][3] = bs3;
        }
#pragma unroll
        for (int nt = 0; nt < 4; ++nt)
#pragma unroll
            for (int kt = 0; kt < 2; ++kt)
                acc[nt] = __builtin_amdgcn_mfma_f32_16x16x32_bf16(
                    afrag[kt], bfrag[nt][kt], acc[nt], 0, 0, 0);

        // GELU -> swizzled LDS staging (alternating 16KB halves of cat_lds)
        float* buf = reinterpret_cast<float*>(cat_lds) + (mt & 1) * 4096;
#pragma unroll
        for (int nt = 0; nt < 4; ++nt) {
            int px = pxb + nt * 16 + lr;
#pragma unroll
            for (int r = 0; r < 4; ++r) {
                int rw = lk * 4 + r;
                float a = acc[nt][r];
                float gl = 0.5f * a * (1.0f + erff(a * 0.70710678118654752f));
                buf[rw * 256 + (px ^ ((rw & 7) << 2))] = gl;
            }
        }
        __syncthreads();

        // prefetch x for next mt (hidden under this round's gating + next MFMA)
        if (mt < 3) {
#pragma unroll
            for (int i = 0; i < 4; ++i)
                xnxt[i] = *reinterpret_cast<const float4*>(
                    &x[goff[i] + (size_t)((mt + 1) * 16) * plane]);
        }

        // coalesced gating: swizzled float4 buf read, float4 store
#pragma unroll
        for (int i = 0; i < 4; ++i) {
            int chLoc = cg + 4 * i;
            float4 gv = *reinterpret_cast<const float4*>(
                &buf[chLoc * 256 + ((q * 4) ^ ((chLoc & 7) << 2))]);
            size_t off = goff[i] + (size_t)(mt * 16) * plane;
            float4 ov;
            ov.x = gv.x * xcur[i].x; ov.y = gv.y * xcur[i].y;
            ov.z = gv.z * xcur[i].z; ov.w = gv.w * xcur[i].w;
            *reinterpret_cast<float4*>(&out[off]) = ov;
        }
#pragma unroll
        for (int i = 0; i < 4; ++i) xcur[i] = xnxt[i];
    }
}

extern "C" void kernel_launch(void* const* d_in, const int* in_sizes, int n_in,
                              void* d_out, int out_size, void* d_ws, size_t ws_size,
                              hipStream_t stream) {
    const float* x  = (const float*)d_in[0];
    const float* w1 = (const float*)d_in[1];
    const float* b1 = (const float*)d_in[2];
    const float* w2 = (const float*)d_in[3];
    const float* b2 = (const float*)d_in[4];
    const float* w3 = (const float*)d_in[5];
    const float* b3 = (const float*)d_in[6];
    const float* w4 = (const float*)d_in[7];
    const float* b4 = (const float*)d_in[8];
    const float* wa = (const float*)d_in[9];
    const float* ba = (const float*)d_in[10];
    float* out = (float*)d_out;

    // Workspace (floats): only the conv outputs are materialized
    float* ws  = (float*)d_ws;
    float* x2c = ws;               // 8*16*64*64 = 524288
    float* x3c = x2c + 524288;     // 8*8*16*16  = 16384
    float* x4c = x3c + 16384;      // 8*8*4*4    = 1024

    // whole pyramid chain in one kernel: one block per (b, c)
    pyramid_kernel<<<NB * 32, 1024, 0, stream>>>(x, w2, b2, w3, b3, w4, b4,
                                                 x2c, x3c, x4c);
    // fused main: one block per (b, h) row (XCD-remapped inside)
    fused_main<<<NB * NH, 256, 0, stream>>>(x, w1, b1, x2c, x3c, x4c, wa, ba, out);
}